// Round 13
// baseline (235.936 us; speedup 1.0000x reference)
//
#include <hip/hip_runtime.h>
#include <hip/hip_bf16.h>

// CTC batch cost — R13: R7's VERIFIED kernel (absmax 0.0, harness 193.20us
// at 1x launch) + 3x idempotent self-timing launch. After four infra
// timeouts on the unverified R9 pipeline kernel, this is the lowest-risk
// attribution measurement: dur = 193.20 + 2k resolves the fused kernel's
// true time k with zero correctness risk. (R7 == R8-pipeline in time, so k
// decides whether the explicit-vmcnt branch is even worth pursuing.)
//
// Kernel structure (R7, unchanged): fully fused single-wave scan; each
// block = one 64-lane wave loading its 5 per-iteration operands directly
// from global (3 divergent gather loads/iter), software-pipelined one
// 8-iteration group ahead via sched_barrier-fenced prefetch arrays; no
// LDS staging, no __syncthreads in the scan. Math bit-identical to the
// verified baseline: f32 (p+EPS)*128 pre-scale, f64 linear-domain
// fwd+bwd meet-in-middle, DPP shifts, readlane broadcasts.
// B=1024, T=256, C=128, L=32, S=65, blank=127.

#define CTC_B 1024
#define CTC_T 256
#define CTC_C 128
#define CTC_L 32
#define CTC_BLANK 127
#define CTC_EPS 1e-7f

#define DPP_WAVE_SHL1 0x130  // lane i <- lane i+1, lane 63 <- 0 (bound_ctrl)
#define DPP_WAVE_SHR1 0x138  // lane i <- lane i-1, lane 0  <- 0 (bound_ctrl)

__device__ __forceinline__ double bperm_f64(int addr, double v) {
    union { double d; int i[2]; } u; u.d = v;
    int x = __builtin_amdgcn_ds_bpermute(addr, u.i[0]);
    int y = __builtin_amdgcn_ds_bpermute(addr, u.i[1]);
    union { int i[2]; double d; } r; r.i[0] = x; r.i[1] = y;
    return r.d;
}

__device__ __forceinline__ double dpp_shr1_f64(double v) {
    union { double d; int i[2]; } u; u.d = v;
    int x = __builtin_amdgcn_update_dpp(0, u.i[0], DPP_WAVE_SHR1, 0xF, 0xF, true);
    int y = __builtin_amdgcn_update_dpp(0, u.i[1], DPP_WAVE_SHR1, 0xF, 0xF, true);
    union { int i[2]; double d; } r; r.i[0] = x; r.i[1] = y;
    return r.d;
}

__device__ __forceinline__ double dpp_shl1_f64(double v) {
    union { double d; int i[2]; } u; u.d = v;
    int x = __builtin_amdgcn_update_dpp(0, u.i[0], DPP_WAVE_SHL1, 0xF, 0xF, true);
    int y = __builtin_amdgcn_update_dpp(0, u.i[1], DPP_WAVE_SHL1, 0xF, 0xF, true);
    union { int i[2]; double d; } r; r.i[0] = x; r.i[1] = y;
    return r.d;
}

__device__ __forceinline__ int dpp_shl1_i32(int v) {
    return __builtin_amdgcn_update_dpp(0, v, DPP_WAVE_SHL1, 0xF, 0xF, true);
}

__device__ __forceinline__ double bcast0_f64(double v) {
    union { double d; int i[2]; } u; u.d = v;
    int x = __builtin_amdgcn_readfirstlane(u.i[0]);
    int y = __builtin_amdgcn_readfirstlane(u.i[1]);
    union { int i[2]; double d; } r; r.i[0] = x; r.i[1] = y;
    return r.d;
}

__global__ __launch_bounds__(64) void ctc_loss_kernel(
    const int* __restrict__ y_true,   // [B, L] int32
    const float* __restrict__ y_pred, // [B, T, C] float32
    float* __restrict__ out)          // [B, 1] float32
{
    const int b = blockIdx.x;
    const int lane = threadIdx.x;

    const float* yp = y_pred + (size_t)b * CTC_T * CTC_C;

    // per-lane label: lanes 0..31 -> y_true, others -> blank
    int lbl = CTC_BLANK;
    if (lane < CTC_L) lbl = y_true[b * CTC_L + lane];

    // ---- per-lane transition constants (identical to verified kernel) ----
    double skip = 0.0;
    if (lane >= 1 && lane < CTC_L) {
        if (y_true[b * CTC_L + lane - 1] != lbl) skip = 1.0;
    }
    double skipn = 0.0;
    if (lane <= 30) {
        if (y_true[b * CTC_L + lane + 1] != lbl) skipn = 1.0;
    } else if (lane == 32) {
        skipn = 1.0;   // reuse v-term as the 0 -> 1 transition
    }
    const bool is32 = (lane == 32);

    // ---- per-lane gather columns (fixed across all rows) ----
    const int col_a = (lane < 32) ? lbl : CTC_BLANK;
    const int lbl_next = dpp_shl1_i32(lbl);                 // lane+1's label
    const int lbl0 = __builtin_amdgcn_readfirstlane(lbl);   // label_0
    const int col_n = (lane <= 31) ? lbl_next
                    : (lane == 32) ? lbl0
                    : CTC_BLANK;

    // ---- init (t=0 row) ----
    double lo = 0.0, hi = 0.0;
    if (lane == 0) {
        lo = (double)((yp[CTC_BLANK] + CTC_EPS) * 128.0f);  // alpha[0]: blank
        hi = (double)((yp[lbl] + CTC_EPS) * 128.0f);        // alpha[1]: label0
    }
    double a = 0.0, bb = 0.0;
    if (lane == 31) { a = 1.0; bb = 1.0; }  // beta_255[63] = beta_255[64] = 1

    // ---- full STEP (bit-identical f64 order to verified kernel) ----
#define STEPK(Ltf, Lta, Ltn) {                                      \
        float vtf = ((Ltf) + CTC_EPS) * 128.0f;                     \
        float vta = ((Lta) + CTC_EPS) * 128.0f;                     \
        float vtn = ((Ltn) + CTC_EPS) * 128.0f;                     \
        float pbf = __int_as_float(                                 \
            __builtin_amdgcn_readlane(__float_as_int(vtf), 32));    \
        float pbbb = __int_as_float(                                \
            __builtin_amdgcn_readlane(__float_as_int(vta), 63));    \
        float pvf  = (lane < 32) ? vtf : 0.0f;                      \
        float paf  = vta;                                           \
        float pa1f = (lane == 31) ? 0.0f : vtn;                     \
        float pbbf = is32 ? 0.0f : pbbb;                            \
        double ph  = dpp_shr1_f64(hi);                              \
        double a1s = dpp_shl1_f64(a);                               \
        double a1  = is32 ? bcast0_f64(a) : a1s;                    \
        double nl = (lo + ph) * (double)pbf;                        \
        double nh = (hi + lo + skip * ph) * (double)pvf;            \
        double v  = (double)pa1f * a1;                              \
        double u  = (double)pbbf * bb;                              \
        double nb = u + v;                                          \
        double na = fma((double)paf, a, fma(skipn, v, u));          \
        lo = nl; hi = nh; a = na; bb = nb;                          \
    }

    // group of 8 slots; slot s of group g is k = 8g+s; fwd row 1+k, bwd 255-k.
#define LOADG(dtf, dta, dtn, g) {                                   \
        _Pragma("unroll")                                           \
        for (int s = 0; s < 8; ++s) {                               \
            const int k = 8 * (g) + s;                              \
            const float* rf = yp + (size_t)(1 + k) * CTC_C;         \
            const float* rb = yp + (size_t)(255 - k) * CTC_C;       \
            dtf[s] = rf[col_a];                                     \
            dta[s] = rb[col_a];                                     \
            dtn[s] = rb[col_n];                                     \
        }                                                           \
    }

    float ctf[8], cta[8], ctn[8];
    float ntf[8], nta[8], ntn[8];

    // prologue: group 0 (k = 0..7)
    LOADG(ctf, cta, ctn, 0);

    // groups 0..14: compute current, prefetch next. (k runs 0..119 here.)
    for (int g = 0; g < 15; ++g) {
        LOADG(ntf, nta, ntn, g + 1);
        __builtin_amdgcn_sched_barrier(0);
        #pragma unroll
        for (int s = 0; s < 8; ++s)
            STEPK(ctf[s], cta[s], ctn[s]);
        __builtin_amdgcn_sched_barrier(0);
        #pragma unroll
        for (int s = 0; s < 8; ++s) {
            ctf[s] = ntf[s]; cta[s] = nta[s]; ctn[s] = ntn[s];
        }
    }

    // group 15: slots 0..6 are full steps (k = 120..126); slot 7 (k = 127)
    // feeds the final backward-only step (row tb = 255-127 = 128).
    #pragma unroll
    for (int s = 0; s < 7; ++s)
        STEPK(ctf[s], cta[s], ctn[s]);

    {   // final backward-only step: row 128 -> beta_127
        float vta = (cta[7] + CTC_EPS) * 128.0f;
        float vtn = (ctn[7] + CTC_EPS) * 128.0f;
        float pbbb = __int_as_float(
            __builtin_amdgcn_readlane(__float_as_int(vta), 63));
        float paf  = vta;
        float pa1f = (lane == 31) ? 0.0f : vtn;
        float pbbf = is32 ? 0.0f : pbbb;
        double a1s = dpp_shl1_f64(a);
        double a1  = is32 ? bcast0_f64(a) : a1s;
        double v  = (double)pa1f * a1;
        double u  = (double)pbbf * bb;
        double nb = u + v;
        double na = fma((double)paf, a, fma(skipn, v, u));
        a = na; bb = nb;
    }
#undef STEPK
#undef LOADG

    // ---- combine: P = sum_s alpha_127[s] * beta_127[s] ----
    // beta[2i]: i=0 -> a_32 (beta[0]); i>=1 -> bb_{i-1}
    double beA = bperm_f64(32 << 2, a);                      // all: a_32
    double beB = bperm_f64(((lane + 63) & 63) << 2, bb);     // bb_{i-1}
    double be = (lane == 0) ? beA : beB;
    double partial = (lane <= 32) ? (lo * be + hi * a) : 0.0;
    #pragma unroll
    for (int off = 32; off >= 1; off >>= 1)
        partial += __shfl_down(partial, off);
    if (lane == 0) {
        out[b] = (float)(1242.1197475634219 - log(partial)); // 256*ln(128)
    }
}

extern "C" void kernel_launch(void* const* d_in, const int* in_sizes, int n_in,
                              void* d_out, int out_size, void* d_ws, size_t ws_size,
                              hipStream_t stream) {
    const int*   y_true = (const int*)d_in[0];
    const float* y_pred = (const float*)d_in[1];
    float*       out    = (float*)d_out;

    // 3x launch for self-timing: kernel is idempotent (pure inputs -> out).
    // R7 measured 193.20us at 1x => dur = 193.20 + 2k.
    ctc_loss_kernel<<<CTC_B, 64, 0, stream>>>(y_true, y_pred, out);
    ctc_loss_kernel<<<CTC_B, 64, 0, stream>>>(y_true, y_pred, out);
    ctc_loss_kernel<<<CTC_B, 64, 0, stream>>>(y_true, y_pred, out);
}